// Round 11
// baseline (1066.329 us; speedup 1.0000x reference)
//
#include <hip/hip_runtime.h>
#include <hip/hip_bf16.h>
#include <math.h>

constexpr int NN  = 16384;
constexpr int DD  = 64;
constexpr int CC  = 128;
constexpr int OO  = 128;
constexpr int KP1 = 17;
constexpr int SIMN = 16384;
constexpr int TW  = 64;              // pruning tile width
constexpr int NT  = SIMN / TW;       // 256 tiles per row
constexpr int CCAP = 1024;           // candidate buffer cap

typedef __attribute__((ext_vector_type(8))) short short8;
typedef __attribute__((ext_vector_type(4))) float floatx4;

__device__ __forceinline__ float bf2f(unsigned short u) {
    union { unsigned u; float f; } c; c.u = ((unsigned)u) << 16; return c.f;
}
__device__ __forceinline__ unsigned short f2bf(float f) {
    union { float f; unsigned u; } c; c.f = f;
    unsigned b = c.u;
    return (unsigned short)((b + 0x7FFFu + ((b >> 16) & 1u)) >> 16);
}

// ---------------------------------------------------------------------------
// Init: deg = 0, nbr = self
// ---------------------------------------------------------------------------
__global__ __launch_bounds__(256)
void k_init(int* __restrict__ deg, int* __restrict__ nbr)
{
    int t = blockIdx.x * 256 + threadIdx.x;
    if (t < NN) deg[t] = 0;
    if (t < NN * KP1) nbr[t] = t / KP1;
}

// ---------------------------------------------------------------------------
// Preprocess v2: 8 nodes/block, 128 threads (thread = channel), fp64 math.
// W rows are loaded once per block and reused by 8 nodes (8x less L2 traffic).
// ---------------------------------------------------------------------------
__global__ __launch_bounds__(128)
void k_pre(const float* __restrict__ x_raw, const float* __restrict__ eps,
           const float* __restrict__ col_logit, const float* __restrict__ type_logit,
           const float* __restrict__ W_enc, const float* __restrict__ b_enc,
           const float* __restrict__ W_mu, const float* __restrict__ b_mu,
           const float* __restrict__ W_lv, const float* __restrict__ b_lv,
           double* __restrict__ zn64, float* __restrict__ z32, float* __restrict__ zn32,
           unsigned short* __restrict__ znb, int use64)
{
    const int tid = threadIdx.x;
    const int n0  = blockIdx.x * 8;
    __shared__ double xg[8][DD];
    __shared__ double hs[8][CC];
    __shared__ double zs[8][CC];
    __shared__ double part[8][16];
    __shared__ double rs_s[8];
    __shared__ double gcol[DD];

    if (tid < DD) {
        double l = (double)col_logit[tid];
        double s = 1.0 / (1.0 + exp(-l * 0.5));
        gcol[tid] = fmin(fmax(s * 1.2 - 0.1, 0.0), 1.0);
    }
    __syncthreads();

    #pragma unroll
    for (int rpt = 0; rpt < 4; rpt++) {
        int idx = tid + rpt * 128;           // 0..511 = 8 nodes x 64 cols
        int m = idx >> 6, d = idx & 63;
        xg[m][d] = (double)x_raw[(size_t)(n0 + m) * DD + d] * gcol[d];
    }
    __syncthreads();

    double tg;
    {
        double l = (double)type_logit[0];
        double s = 1.0 / (1.0 + exp(-l * 0.5));
        tg = fmin(fmax(s * 1.2 - 0.1, 0.0), 1.0);
    }

    double h[8];
    #pragma unroll
    for (int m = 0; m < 8; m++) h[m] = (double)b_enc[tid];
    for (int d = 0; d < DD; d++) {
        double w = (double)W_enc[d * CC + tid];
        #pragma unroll
        for (int m = 0; m < 8; m++) h[m] += xg[m][d] * w;
    }
    #pragma unroll
    for (int m = 0; m < 8; m++) hs[m][tid] = h[m] * tg;
    __syncthreads();

    double mu[8], lv[8];
    #pragma unroll
    for (int m = 0; m < 8; m++) { mu[m] = (double)b_mu[tid]; lv[m] = (double)b_lv[tid]; }
    for (int j = 0; j < CC; j++) {
        double wm = (double)W_mu[j * CC + tid];
        double wl = (double)W_lv[j * CC + tid];
        #pragma unroll
        for (int m = 0; m < 8; m++) { double hj = hs[m][j]; mu[m] += hj * wm; lv[m] += hj * wl; }
    }
    #pragma unroll
    for (int m = 0; m < 8; m++) {
        double l = fmin(fmax(lv[m], -10.0), 10.0);
        zs[m][tid] = mu[m] + (double)eps[(size_t)(n0 + m) * CC + tid] * exp(0.5 * l);
    }
    __syncthreads();

    // sum of squares: 16 threads per node
    {
        int m = tid >> 4, t = tid & 15;
        double s = 0.0;
        for (int c = t; c < CC; c += 16) { double z = zs[m][c]; s += z * z; }
        part[m][t] = s;
    }
    __syncthreads();
    if (tid < 8) {
        double s = 0.0;
        for (int t = 0; t < 16; t++) s += part[tid][t];
        rs_s[tid] = 1.0 / sqrt(s + 1e-12);
    }
    __syncthreads();

    #pragma unroll
    for (int m = 0; m < 8; m++) {
        double z  = zs[m][tid];
        double zn = z * rs_s[m];
        size_t o  = (size_t)(n0 + m) * CC + tid;
        if (use64) zn64[o] = zn;
        z32[o]  = (float)z;
        float znf = (float)zn;
        zn32[o] = znf;
        znb[o]  = f2bf(znf);
    }
}

// ---------------------------------------------------------------------------
// Sim v3: MFMA with direct-global fragment loads (znb is L2-resident, 4 MB).
// Grid (S/128, 32). Block = 4 waves; each wave a 64x64 quadrant of a 128x128
// C tile. A-frags held in registers across 4 column-tiles. LDS only stages
// rounded-bf16 C for coalesced stores. simmax computed from rounded values.
// ---------------------------------------------------------------------------
__global__ __launch_bounds__(256)
void k_sim(const unsigned short* __restrict__ znb, int row0,
           unsigned short* __restrict__ sim, float* __restrict__ simmax)
{
    __shared__ __align__(16) unsigned short ldsC[128 * 128];   // 32 KB
    const int tid  = threadIdx.x;
    const int lane = tid & 63;
    const int wv   = tid >> 6;
    const int am0  = row0 + blockIdx.x * 128;
    const int cg0  = blockIdx.y * 512;
    const int mq   = (wv & 1) * 64;
    const int nq   = (wv >> 1) * 64;
    const int lm   = lane & 15;
    const int lk   = lane >> 4;

    // preload A fragments (rows am0+mq.., all K) into registers
    short8 af[4][4];   // [kt][mt]
    #pragma unroll
    for (int mt = 0; mt < 4; mt++) {
        const unsigned short* ap = znb + (size_t)(am0 + mq + mt * 16 + lm) * CC;
        #pragma unroll
        for (int kt = 0; kt < 4; kt++)
            af[kt][mt] = *(const short8*)&ap[kt * 32 + lk * 8];
    }

    for (int bt = 0; bt < 4; bt++) {
        const int bn0 = cg0 + bt * 128;
        floatx4 acc[4][4];
        #pragma unroll
        for (int i = 0; i < 4; i++)
            #pragma unroll
            for (int j = 0; j < 4; j++) acc[i][j] = (floatx4){0.f, 0.f, 0.f, 0.f};

        #pragma unroll
        for (int nt = 0; nt < 4; nt++) {
            const unsigned short* bp = znb + (size_t)(bn0 + nq + nt * 16 + lm) * CC;
            #pragma unroll
            for (int kt = 0; kt < 4; kt++) {
                short8 bf8 = *(const short8*)&bp[kt * 32 + lk * 8];
                #pragma unroll
                for (int mt = 0; mt < 4; mt++)
                    acc[mt][nt] = __builtin_amdgcn_mfma_f32_16x16x32_bf16(
                        af[kt][mt], bf8, acc[mt][nt], 0, 0, 0);
            }
        }

        // round to bf16, stage into LDS (swizzled), track per-row 64-col max
        #pragma unroll
        for (int mt = 0; mt < 4; mt++)
            #pragma unroll
            for (int rg = 0; rg < 4; rg++) {
                int m = mq + mt * 16 + lk * 4 + rg;
                float mx = -3.0e38f;
                #pragma unroll
                for (int nt = 0; nt < 4; nt++) {
                    unsigned short hw = f2bf(acc[mt][nt][rg]);
                    int n = nq + nt * 16 + lm;
                    int pc = ((n >> 3) ^ (m & 15)) * 8 + (n & 7);
                    ldsC[m * 128 + pc] = hw;
                    mx = fmaxf(mx, bf2f(hw));
                }
                #pragma unroll
                for (int s = 1; s < 16; s <<= 1) mx = fmaxf(mx, __shfl_xor(mx, s));
                if (lm == 0) {
                    int lrow = blockIdx.x * 128 + m;
                    int gtile = cg0 / 64 + bt * 2 + (wv >> 1);
                    simmax[(size_t)lrow * NT + gtile] = mx;
                }
            }
        __syncthreads();

        // coalesced writeout: thread -> (row = tid>>1, half = tid&1)
        {
            int rr = tid >> 1, half = tid & 1;
            int lrow = blockIdx.x * 128 + rr;
            unsigned short* dst = sim + (size_t)lrow * SIMN + bn0 + half * 64;
            #pragma unroll
            for (int t = 0; t < 8; t++) {
                int c = half * 8 + t;
                int pc = (c ^ (rr & 15)) * 8;
                *(short8*)&dst[t * 8] = *(const short8*)&ldsC[rr * 128 + pc];
            }
        }
        __syncthreads();
    }
}

// ---------------------------------------------------------------------------
// Top-k v4 (rank-count), bf16 sim input.
// ---------------------------------------------------------------------------
__global__ __launch_bounds__(256)
void k_topk(const unsigned short* __restrict__ sim, const float* __restrict__ simmax,
            int row0, const double* __restrict__ zn64, const float* __restrict__ zn32,
            int* __restrict__ nbr, int use64)
{
    const int lr  = blockIdx.x;
    const int r   = row0 + lr;
    const int tid = threadIdx.x;

    __shared__ float  smax[NT];
    __shared__ float  Lsh;
    __shared__ int    tlist[NT];
    __shared__ int    tcnt;
    __shared__ float  cval[CCAP];
    __shared__ int    cidx[CCAP];
    __shared__ int    ccnt;
    __shared__ int    gi[32];
    __shared__ double q[CC];
    __shared__ double dv[32];

    if (tid == 0) { tcnt = 0; ccnt = 0; }
    if (tid < 32) gi[tid] = r;               // safe default (self)
    smax[tid] = simmax[(size_t)lr * NT + tid];
    __syncthreads();

    // ---- P0: 32nd-largest tile-max via rank count ----
    {
        float v = smax[tid];
        int rank = 0;
        for (int j = 0; j < NT; j++) {
            float w = smax[j];
            rank += (w > v || (w == v && j < tid)) ? 1 : 0;
        }
        if (rank == 31) Lsh = v;
    }
    __syncthreads();
    const float L = Lsh;

    // ---- P1a: surviving tile list ----
    if (smax[tid] >= L) { int p = atomicAdd(&tcnt, 1); tlist[p] = tid; }
    __syncthreads();
    const int Scnt = tcnt;

    // ---- P1b: scan survivors (bf16), append candidates >= L ----
    const unsigned short* srow = sim + (size_t)lr * SIMN;
    const int total8 = Scnt * (TW / 8);
    for (int idx = tid; idx < total8; idx += 256) {
        int tile = tlist[idx >> 3];
        int col0 = tile * TW + (idx & 7) * 8;
        short8 v8 = *(const short8*)&srow[col0];
        #pragma unroll
        for (int e = 0; e < 8; e++) {
            float v = bf2f((unsigned short)v8[e]);
            if (v >= L) {
                int p = atomicAdd(&ccnt, 1);
                if (p < CCAP) { cval[p] = v; cidx[p] = col0 + e; }
            }
        }
    }
    __syncthreads();
    int C = ccnt; if (C > CCAP) C = CCAP;

    // ---- P2: top-32 by lex rank over candidates ----
    for (int c = tid; c < C; c += 256) {
        float v = cval[c]; int ix = cidx[c];
        int rank = 0;
        for (int j = 0; j < C; j++) {
            float w = cval[j];
            rank += (w > v || (w == v && cidx[j] < ix)) ? 1 : 0;
        }
        if (rank < 32) gi[rank] = ix;
    }
    __syncthreads();

    // ---- P3: fp64 re-rank of 32 candidates ----
    if (tid < CC) {
        q[tid] = use64 ? zn64[(size_t)r * CC + tid] : (double)zn32[(size_t)r * CC + tid];
    }
    __syncthreads();
    if (tid < 32) {
        int cx = gi[tid];
        if ((unsigned)cx >= (unsigned)NN) cx = 0;
        double s = 0.0;
        if (use64) {
            const double* zr = zn64 + (size_t)cx * CC;
            for (int k = 0; k < CC; k++) s += q[k] * zr[k];
        } else {
            const float* zr = zn32 + (size_t)cx * CC;
            for (int k = 0; k < CC; k++) s += q[k] * (double)zr[k];
        }
        dv[tid] = s;
    }
    __syncthreads();

    // ---- P4: top-17 by rank count over the 32 ----
    if (tid < 32) {
        double v = dv[tid]; int ix = gi[tid];
        int rank = 0;
        for (int j = 0; j < 32; j++) {
            double w = dv[j];
            rank += (w > v || (w == v && gi[j] < ix)) ? 1 : 0;
        }
        if (rank < KP1) nbr[(size_t)r * KP1 + rank] = ix;
    }
}

// ---------------------------------------------------------------------------
// CSR build: count -> scan -> fill. All index-guarded.
// ---------------------------------------------------------------------------
__global__ __launch_bounds__(256)
void k_count(const int* __restrict__ nbr, int* __restrict__ deg)
{
    int e = blockIdx.x * 256 + threadIdx.x;
    if (e >= NN * KP1) return;
    int i = e / KP1;
    int dst = nbr[e];
    if (dst != i && (unsigned)dst < (unsigned)NN) atomicAdd(&deg[dst], 1);
}

__global__ __launch_bounds__(256)
void k_scan(const int* __restrict__ deg, int* __restrict__ rp, int* __restrict__ wp)
{
    __shared__ int s[256];
    __shared__ int carry;
    const int tid = threadIdx.x;
    if (tid == 0) carry = 0;
    __syncthreads();
    for (int ch = 0; ch < NN / 256; ch++) {
        int v = deg[ch * 256 + tid];
        s[tid] = v;
        __syncthreads();
        for (int off2 = 1; off2 < 256; off2 <<= 1) {
            int t = (tid >= off2) ? s[tid - off2] : 0;
            __syncthreads();
            s[tid] += t;
            __syncthreads();
        }
        int inc = s[tid];
        int base = carry;
        rp[ch * 256 + tid + 1] = base + inc;
        wp[ch * 256 + tid]     = base + inc - v;
        __syncthreads();
        if (tid == 255) carry = base + inc;
        __syncthreads();
    }
    if (tid == 0) rp[0] = 0;
}

__global__ __launch_bounds__(256)
void k_fill(const int* __restrict__ nbr, int* __restrict__ wp, int* __restrict__ es)
{
    int e = blockIdx.x * 256 + threadIdx.x;
    if (e >= NN * KP1) return;
    int i = e / KP1;
    int dst = nbr[e];
    if (dst != i && (unsigned)dst < (unsigned)NN) {
        int pos = atomicAdd(&wp[dst], 1);
        if ((unsigned)pos < (unsigned)(NN * KP1)) es[pos] = i;
    }
}

// ---------------------------------------------------------------------------
// Mean of in-neighbors
// ---------------------------------------------------------------------------
__global__ __launch_bounds__(128)
void k_gather(const float* __restrict__ x, const int* __restrict__ rp,
              const int* __restrict__ es, float* __restrict__ meanb)
{
    int n = blockIdx.x, c = threadIdx.x;
    int b = rp[n], e2 = rp[n + 1];
    if (b < 0) b = 0;
    if (e2 > NN * KP1) e2 = NN * KP1;
    float acc = 0.f;
    int cnt = 0;
    for (int t = b; t < e2; t++) {
        int s = es[t];
        if ((unsigned)s < (unsigned)NN) { acc += x[(size_t)s * CC + c]; cnt++; }
    }
    meanb[(size_t)n * CC + c] = acc / fmaxf((float)cnt, 1.0f);
}

// ---------------------------------------------------------------------------
// SAGE layer: out = relu(a@Ws + mean@Wn + b), 8 nodes/block
// ---------------------------------------------------------------------------
__global__ __launch_bounds__(128)
void k_layer(const float* __restrict__ a, const float* __restrict__ mb,
             const float* __restrict__ Ws, const float* __restrict__ Wn,
             const float* __restrict__ bias, float* __restrict__ out)
{
    __shared__ float as[8][CC], ms[8][CC];
    const int tid = threadIdx.x;
    const int n0 = blockIdx.x * 8;
    #pragma unroll
    for (int m = 0; m < 8; m++) {
        as[m][tid] = a[(size_t)(n0 + m) * CC + tid];
        ms[m][tid] = mb[(size_t)(n0 + m) * CC + tid];
    }
    __syncthreads();
    float acc[8];
    #pragma unroll
    for (int m = 0; m < 8; m++) acc[m] = bias[tid];
    for (int j = 0; j < CC; j++) {
        float ws = Ws[j * CC + tid], wn = Wn[j * CC + tid];
        #pragma unroll
        for (int m = 0; m < 8; m++) acc[m] += as[m][j] * ws + ms[m][j] * wn;
    }
    #pragma unroll
    for (int m = 0; m < 8; m++)
        out[(size_t)(n0 + m) * CC + tid] = fmaxf(acc[m], 0.f);
}

// ---------------------------------------------------------------------------
// Head: out = h2 @ W_head + b_head, fp32 output
// ---------------------------------------------------------------------------
__global__ __launch_bounds__(128)
void k_head(const float* __restrict__ h2, const float* __restrict__ W,
            const float* __restrict__ bias, float* __restrict__ out)
{
    __shared__ float hsh[8][CC];
    const int tid = threadIdx.x;
    const int n0 = blockIdx.x * 8;
    #pragma unroll
    for (int m = 0; m < 8; m++) hsh[m][tid] = h2[(size_t)(n0 + m) * CC + tid];
    __syncthreads();
    float acc[8];
    #pragma unroll
    for (int m = 0; m < 8; m++) acc[m] = bias[tid];
    for (int j = 0; j < CC; j++) {
        float w = W[j * OO + tid];
        #pragma unroll
        for (int m = 0; m < 8; m++) acc[m] += hsh[m][j] * w;
    }
    #pragma unroll
    for (int m = 0; m < 8; m++)
        out[(size_t)(n0 + m) * OO + tid] = acc[m];
}

// ---------------------------------------------------------------------------
extern "C" void kernel_launch(void* const* d_in, const int* in_sizes, int n_in,
                              void* d_out, int out_size, void* d_ws, size_t ws_size,
                              hipStream_t stream)
{
    const float* x_raw      = (const float*)d_in[0];
    const float* eps        = (const float*)d_in[1];
    const float* col_logit  = (const float*)d_in[2];
    const float* type_logit = (const float*)d_in[3];
    const float* W_enc      = (const float*)d_in[4];
    const float* b_enc      = (const float*)d_in[5];
    const float* W_mu       = (const float*)d_in[6];
    const float* b_mu       = (const float*)d_in[7];
    const float* W_lv       = (const float*)d_in[8];
    const float* b_lv       = (const float*)d_in[9];
    const float* W_self1    = (const float*)d_in[10];
    const float* W_nbr1     = (const float*)d_in[11];
    const float* b1         = (const float*)d_in[12];
    const float* W_self2    = (const float*)d_in[13];
    const float* W_nbr2     = (const float*)d_in[14];
    const float* b2         = (const float*)d_in[15];
    const float* W_head     = (const float*)d_in[16];
    const float* b_head     = (const float*)d_in[17];
    float* out              = (float*)d_out;   // fp32 output, per reference dtype

    char* base = (char*)d_ws;
    size_t off = 0;
    auto alloc = [&](size_t bytes) { size_t o = off; off = (off + bytes + 255) & ~(size_t)255; return o; };

    const size_t MAT  = (size_t)NN * CC * 4;   // 8.39 MB

    float* z32    = (float*)(base + alloc(MAT));
    float* zn32   = (float*)(base + alloc(MAT));
    float* slotD  = (float*)(base + alloc(MAT));   // sim overlay (S=128) then h1
    float* meanb  = (float*)(base + alloc(MAT));
    unsigned short* znb = (unsigned short*)(base + alloc((size_t)NN * CC * 2));  // 4 MB
    float* simmax = (float*)(base + alloc((size_t)2048 * NT * 4));  // 2 MB (max stripe)
    int*   nbr    = (int*)(base + alloc((size_t)NN * KP1 * 4));
    int*   deg    = (int*)(base + alloc((size_t)NN * 4));
    int*   rp     = (int*)(base + alloc((size_t)(NN + 1) * 4));
    int*   wp     = (int*)(base + alloc((size_t)NN * 4));
    int*   es     = (int*)(base + alloc((size_t)NN * KP1 * 4));
    size_t fixed_small = off;

    // optional fp64 zn (16.78 MB)
    int use64 = (ws_size >= fixed_small + (size_t)NN * CC * 8 + 4096) ? 1 : 0;
    double* zn64 = nullptr;
    if (use64) zn64 = (double*)(base + alloc((size_t)NN * CC * 8));

    // sim stripe (bf16): dedicated if it fits, else S=128 overlay in slotD
    size_t avail = (ws_size > off) ? (ws_size - off - 4096) : 0;
    int S = 2048;
    while (S > 128 && (size_t)S * SIMN * 2 > avail) S >>= 1;
    unsigned short* sim;
    if ((size_t)S * SIMN * 2 <= avail && S > 128) {
        sim = (unsigned short*)(base + alloc((size_t)S * SIMN * 2));
    } else {
        S = 128;                                  // 4 MB, fits in slotD (8.39 MB)
        sim = (unsigned short*)slotD;
    }

    float* h1 = slotD;                            // after stripes, slotD becomes h1
    float* h2 = zn32;                             // zn32 dead after topk

    k_init<<<(NN * KP1 + 255) / 256, 256, 0, stream>>>(deg, nbr);

    k_pre<<<NN / 8, 128, 0, stream>>>(x_raw, eps, col_logit, type_logit,
                                      W_enc, b_enc, W_mu, b_mu, W_lv, b_lv,
                                      zn64, z32, zn32, znb, use64);

    for (int row0 = 0; row0 < NN; row0 += S) {
        dim3 g(S / 128, SIMN / 512);
        k_sim<<<g, 256, 0, stream>>>(znb, row0, sim, simmax);
        k_topk<<<S, 256, 0, stream>>>(sim, simmax, row0, zn64, zn32, nbr, use64);
    }

    int eb = (NN * KP1 + 255) / 256;
    k_count<<<eb, 256, 0, stream>>>(nbr, deg);
    k_scan<<<1, 256, 0, stream>>>(deg, rp, wp);
    k_fill<<<eb, 256, 0, stream>>>(nbr, wp, es);

    k_gather<<<NN, 128, 0, stream>>>(z32, rp, es, meanb);
    k_layer<<<NN / 8, 128, 0, stream>>>(z32, meanb, W_self1, W_nbr1, b1, h1);
    k_gather<<<NN, 128, 0, stream>>>(h1, rp, es, meanb);
    k_layer<<<NN / 8, 128, 0, stream>>>(h1, meanb, W_self2, W_nbr2, b2, h2);
    k_head<<<NN / 8, 128, 0, stream>>>(h2, W_head, b_head, out);

    (void)in_sizes; (void)n_in; (void)out_size;
}

// Round 12
// 996.080 us; speedup vs baseline: 1.0705x; 1.0705x over previous
//
#include <hip/hip_runtime.h>
#include <hip/hip_bf16.h>
#include <math.h>

constexpr int NN  = 16384;
constexpr int DD  = 64;
constexpr int CC  = 128;
constexpr int OO  = 128;
constexpr int KP1 = 17;
constexpr int SIMN = 16384;
constexpr int TW  = 64;              // pruning tile width
constexpr int NT  = SIMN / TW;       // 256 tiles per row
constexpr int CCAP = 1024;           // candidate buffer cap

typedef __attribute__((ext_vector_type(8))) short short8;
typedef __attribute__((ext_vector_type(4))) float floatx4;

__device__ __forceinline__ float bf2f(unsigned short u) {
    union { unsigned u; float f; } c; c.u = ((unsigned)u) << 16; return c.f;
}
__device__ __forceinline__ unsigned short f2bf(float f) {
    union { float f; unsigned u; } c; c.f = f;
    unsigned b = c.u;
    return (unsigned short)((b + 0x7FFFu + ((b >> 16) & 1u)) >> 16);
}

// ---------------------------------------------------------------------------
// Init: deg = 0, nbr = self
// ---------------------------------------------------------------------------
__global__ __launch_bounds__(256)
void k_init(int* __restrict__ deg, int* __restrict__ nbr)
{
    int t = blockIdx.x * 256 + threadIdx.x;
    if (t < NN) deg[t] = 0;
    if (t < NN * KP1) nbr[t] = t / KP1;
}

// ---------------------------------------------------------------------------
// Preprocess: 8 nodes/block, 128 threads (thread = channel), fp64 math.
// ---------------------------------------------------------------------------
__global__ __launch_bounds__(128)
void k_pre(const float* __restrict__ x_raw, const float* __restrict__ eps,
           const float* __restrict__ col_logit, const float* __restrict__ type_logit,
           const float* __restrict__ W_enc, const float* __restrict__ b_enc,
           const float* __restrict__ W_mu, const float* __restrict__ b_mu,
           const float* __restrict__ W_lv, const float* __restrict__ b_lv,
           double* __restrict__ zn64, float* __restrict__ z32, float* __restrict__ zn32,
           unsigned short* __restrict__ znb, int use64)
{
    const int tid = threadIdx.x;
    const int n0  = blockIdx.x * 8;
    __shared__ double xg[8][DD];
    __shared__ double hs[8][CC];
    __shared__ double zs[8][CC];
    __shared__ double part[8][16];
    __shared__ double rs_s[8];
    __shared__ double gcol[DD];

    if (tid < DD) {
        double l = (double)col_logit[tid];
        double s = 1.0 / (1.0 + exp(-l * 0.5));
        gcol[tid] = fmin(fmax(s * 1.2 - 0.1, 0.0), 1.0);
    }
    __syncthreads();

    #pragma unroll
    for (int rpt = 0; rpt < 4; rpt++) {
        int idx = tid + rpt * 128;           // 0..511 = 8 nodes x 64 cols
        int m = idx >> 6, d = idx & 63;
        xg[m][d] = (double)x_raw[(size_t)(n0 + m) * DD + d] * gcol[d];
    }
    __syncthreads();

    double tg;
    {
        double l = (double)type_logit[0];
        double s = 1.0 / (1.0 + exp(-l * 0.5));
        tg = fmin(fmax(s * 1.2 - 0.1, 0.0), 1.0);
    }

    double h[8];
    #pragma unroll
    for (int m = 0; m < 8; m++) h[m] = (double)b_enc[tid];
    for (int d = 0; d < DD; d++) {
        double w = (double)W_enc[d * CC + tid];
        #pragma unroll
        for (int m = 0; m < 8; m++) h[m] += xg[m][d] * w;
    }
    #pragma unroll
    for (int m = 0; m < 8; m++) hs[m][tid] = h[m] * tg;
    __syncthreads();

    double mu[8], lv[8];
    #pragma unroll
    for (int m = 0; m < 8; m++) { mu[m] = (double)b_mu[tid]; lv[m] = (double)b_lv[tid]; }
    for (int j = 0; j < CC; j++) {
        double wm = (double)W_mu[j * CC + tid];
        double wl = (double)W_lv[j * CC + tid];
        #pragma unroll
        for (int m = 0; m < 8; m++) { double hj = hs[m][j]; mu[m] += hj * wm; lv[m] += hj * wl; }
    }
    #pragma unroll
    for (int m = 0; m < 8; m++) {
        double l = fmin(fmax(lv[m], -10.0), 10.0);
        zs[m][tid] = mu[m] + (double)eps[(size_t)(n0 + m) * CC + tid] * exp(0.5 * l);
    }
    __syncthreads();

    {
        int m = tid >> 4, t = tid & 15;
        double s = 0.0;
        for (int c = t; c < CC; c += 16) { double z = zs[m][c]; s += z * z; }
        part[m][t] = s;
    }
    __syncthreads();
    if (tid < 8) {
        double s = 0.0;
        for (int t = 0; t < 16; t++) s += part[tid][t];
        rs_s[tid] = 1.0 / sqrt(s + 1e-12);
    }
    __syncthreads();

    #pragma unroll
    for (int m = 0; m < 8; m++) {
        double z  = zs[m][tid];
        double zn = z * rs_s[m];
        size_t o  = (size_t)(n0 + m) * CC + tid;
        if (use64) zn64[o] = zn;
        z32[o]  = (float)z;
        float znf = (float)zn;
        zn32[o] = znf;
        znb[o]  = f2bf(znf);
    }
}

// ---------------------------------------------------------------------------
// Sim v4: MFMA, direct-global fragment loads, ONE 128x128 C tile per block
// (grid S/128 x 128 -> 2048 blocks: occupancy over reuse). LDS stages rounded
// bf16 C for coalesced stores; simmax from rounded values.
// ---------------------------------------------------------------------------
__global__ __launch_bounds__(256)
void k_sim(const unsigned short* __restrict__ znb, int row0,
           unsigned short* __restrict__ sim, float* __restrict__ simmax)
{
    __shared__ __align__(16) unsigned short ldsC[128 * 128];   // 32 KB
    const int tid  = threadIdx.x;
    const int lane = tid & 63;
    const int wv   = tid >> 6;
    const int am0  = row0 + blockIdx.x * 128;
    const int bn0  = blockIdx.y * 128;
    const int mq   = (wv & 1) * 64;
    const int nq   = (wv >> 1) * 64;
    const int lm   = lane & 15;
    const int lk   = lane >> 4;

    // A fragments (rows am0+mq.., all K)
    short8 af[4][4];   // [kt][mt]
    #pragma unroll
    for (int mt = 0; mt < 4; mt++) {
        const unsigned short* ap = znb + (size_t)(am0 + mq + mt * 16 + lm) * CC;
        #pragma unroll
        for (int kt = 0; kt < 4; kt++)
            af[kt][mt] = *(const short8*)&ap[kt * 32 + lk * 8];
    }

    floatx4 acc[4][4];
    #pragma unroll
    for (int i = 0; i < 4; i++)
        #pragma unroll
        for (int j = 0; j < 4; j++) acc[i][j] = (floatx4){0.f, 0.f, 0.f, 0.f};

    #pragma unroll
    for (int nt = 0; nt < 4; nt++) {
        const unsigned short* bp = znb + (size_t)(bn0 + nq + nt * 16 + lm) * CC;
        #pragma unroll
        for (int kt = 0; kt < 4; kt++) {
            short8 bf8 = *(const short8*)&bp[kt * 32 + lk * 8];
            #pragma unroll
            for (int mt = 0; mt < 4; mt++)
                acc[mt][nt] = __builtin_amdgcn_mfma_f32_16x16x32_bf16(
                    af[kt][mt], bf8, acc[mt][nt], 0, 0, 0);
        }
    }

    // round to bf16, stage into LDS (swizzled), per-row 64-col max
    #pragma unroll
    for (int mt = 0; mt < 4; mt++)
        #pragma unroll
        for (int rg = 0; rg < 4; rg++) {
            int m = mq + mt * 16 + lk * 4 + rg;
            float mx = -3.0e38f;
            #pragma unroll
            for (int nt = 0; nt < 4; nt++) {
                unsigned short hw = f2bf(acc[mt][nt][rg]);
                int n = nq + nt * 16 + lm;
                int pc = ((n >> 3) ^ (m & 15)) * 8 + (n & 7);
                ldsC[m * 128 + pc] = hw;
                mx = fmaxf(mx, bf2f(hw));
            }
            #pragma unroll
            for (int s = 1; s < 16; s <<= 1) mx = fmaxf(mx, __shfl_xor(mx, s));
            if (lm == 0) {
                int lrow = blockIdx.x * 128 + m;
                int gtile = blockIdx.y * 2 + (wv >> 1);
                simmax[(size_t)lrow * NT + gtile] = mx;
            }
        }
    __syncthreads();

    // coalesced writeout
    {
        int rr = tid >> 1, half = tid & 1;
        int lrow = blockIdx.x * 128 + rr;
        unsigned short* dst = sim + (size_t)lrow * SIMN + bn0 + half * 64;
        #pragma unroll
        for (int t = 0; t < 8; t++) {
            int c = half * 8 + t;
            int pc = (c ^ (rr & 15)) * 8;
            *(short8*)&dst[t * 8] = *(const short8*)&ldsC[rr * 128 + pc];
        }
    }
}

// ---------------------------------------------------------------------------
// Top-k (rank-count), bf16 sim input. Also accumulates deg (replaces k_count).
// ---------------------------------------------------------------------------
__global__ __launch_bounds__(256)
void k_topk(const unsigned short* __restrict__ sim, const float* __restrict__ simmax,
            int row0, const double* __restrict__ zn64, const float* __restrict__ zn32,
            int* __restrict__ nbr, int* __restrict__ deg, int use64)
{
    const int lr  = blockIdx.x;
    const int r   = row0 + lr;
    const int tid = threadIdx.x;

    __shared__ float  smax[NT];
    __shared__ float  Lsh;
    __shared__ int    tlist[NT];
    __shared__ int    tcnt;
    __shared__ float  cval[CCAP];
    __shared__ int    cidx[CCAP];
    __shared__ int    ccnt;
    __shared__ int    gi[32];
    __shared__ double q[CC];
    __shared__ double dv[32];

    if (tid == 0) { tcnt = 0; ccnt = 0; }
    if (tid < 32) gi[tid] = r;               // safe default (self)
    smax[tid] = simmax[(size_t)lr * NT + tid];
    __syncthreads();

    // ---- P0: 32nd-largest tile-max via rank count ----
    {
        float v = smax[tid];
        int rank = 0;
        for (int j = 0; j < NT; j++) {
            float w = smax[j];
            rank += (w > v || (w == v && j < tid)) ? 1 : 0;
        }
        if (rank == 31) Lsh = v;
    }
    __syncthreads();
    const float L = Lsh;

    // ---- P1a: surviving tile list ----
    if (smax[tid] >= L) { int p = atomicAdd(&tcnt, 1); tlist[p] = tid; }
    __syncthreads();
    const int Scnt = tcnt;

    // ---- P1b: scan survivors (bf16), append candidates >= L ----
    const unsigned short* srow = sim + (size_t)lr * SIMN;
    const int total8 = Scnt * (TW / 8);
    for (int idx = tid; idx < total8; idx += 256) {
        int tile = tlist[idx >> 3];
        int col0 = tile * TW + (idx & 7) * 8;
        short8 v8 = *(const short8*)&srow[col0];
        #pragma unroll
        for (int e = 0; e < 8; e++) {
            float v = bf2f((unsigned short)v8[e]);
            if (v >= L) {
                int p = atomicAdd(&ccnt, 1);
                if (p < CCAP) { cval[p] = v; cidx[p] = col0 + e; }
            }
        }
    }
    __syncthreads();
    int C = ccnt; if (C > CCAP) C = CCAP;

    // ---- P2: top-32 by lex rank over candidates ----
    for (int c = tid; c < C; c += 256) {
        float v = cval[c]; int ix = cidx[c];
        int rank = 0;
        for (int j = 0; j < C; j++) {
            float w = cval[j];
            rank += (w > v || (w == v && cidx[j] < ix)) ? 1 : 0;
        }
        if (rank < 32) gi[rank] = ix;
    }
    __syncthreads();

    // ---- P3: fp64 re-rank of 32 candidates ----
    if (tid < CC) {
        q[tid] = use64 ? zn64[(size_t)r * CC + tid] : (double)zn32[(size_t)r * CC + tid];
    }
    __syncthreads();
    if (tid < 32) {
        int cx = gi[tid];
        if ((unsigned)cx >= (unsigned)NN) cx = 0;
        double s = 0.0;
        if (use64) {
            const double* zr = zn64 + (size_t)cx * CC;
            for (int k = 0; k < CC; k++) s += q[k] * zr[k];
        } else {
            const float* zr = zn32 + (size_t)cx * CC;
            for (int k = 0; k < CC; k++) s += q[k] * (double)zr[k];
        }
        dv[tid] = s;
    }
    __syncthreads();

    // ---- P4: top-17 by rank count; emit nbr + deg ----
    if (tid < 32) {
        double v = dv[tid]; int ix = gi[tid];
        int rank = 0;
        for (int j = 0; j < 32; j++) {
            double w = dv[j];
            rank += (w > v || (w == v && gi[j] < ix)) ? 1 : 0;
        }
        if (rank < KP1) {
            nbr[(size_t)r * KP1 + rank] = ix;
            if (ix != r && (unsigned)ix < (unsigned)NN) atomicAdd(&deg[ix], 1);
        }
    }
}

// ---------------------------------------------------------------------------
// Scan v2: one block, 256 threads x 64 contiguous elements; wave shuffle scan
// + 4-entry LDS combine. 2 barriers total (was ~1024).
// ---------------------------------------------------------------------------
__global__ __launch_bounds__(256)
void k_scan(const int* __restrict__ deg, int* __restrict__ rp, int* __restrict__ wp)
{
    const int tid  = threadIdx.x;
    const int lane = tid & 63;
    const int wv   = tid >> 6;
    const int base = tid * 64;

    int v[64];
    int sum = 0;
    #pragma unroll
    for (int i = 0; i < 16; i++) {
        int4 t = *(const int4*)&deg[base + i * 4];
        v[i*4+0] = t.x; v[i*4+1] = t.y; v[i*4+2] = t.z; v[i*4+3] = t.w;
        sum += t.x + t.y + t.z + t.w;
    }

    int inc = sum;
    #pragma unroll
    for (int off2 = 1; off2 < 64; off2 <<= 1) {
        int o = __shfl_up(inc, off2);
        if (lane >= off2) inc += o;
    }

    __shared__ int wtot[4];
    if (lane == 63) wtot[wv] = inc;
    __syncthreads();
    int woff = 0;
    for (int w = 0; w < wv; w++) woff += wtot[w];

    int run = woff + inc - sum;        // exclusive prefix of this thread's chunk
    #pragma unroll
    for (int i = 0; i < 64; i++) {
        wp[base + i] = run;
        run += v[i];
        rp[base + i + 1] = run;
    }
    if (tid == 0) rp[0] = 0;
}

__global__ __launch_bounds__(256)
void k_fill(const int* __restrict__ nbr, int* __restrict__ wp, int* __restrict__ es)
{
    int e = blockIdx.x * 256 + threadIdx.x;
    if (e >= NN * KP1) return;
    int i = e / KP1;
    int dst = nbr[e];
    if (dst != i && (unsigned)dst < (unsigned)NN) {
        int pos = atomicAdd(&wp[dst], 1);
        if ((unsigned)pos < (unsigned)(NN * KP1)) es[pos] = i;
    }
}

// ---------------------------------------------------------------------------
// Mean of in-neighbors
// ---------------------------------------------------------------------------
__global__ __launch_bounds__(128)
void k_gather(const float* __restrict__ x, const int* __restrict__ rp,
              const int* __restrict__ es, float* __restrict__ meanb)
{
    int n = blockIdx.x, c = threadIdx.x;
    int b = rp[n], e2 = rp[n + 1];
    if (b < 0) b = 0;
    if (e2 > NN * KP1) e2 = NN * KP1;
    float acc = 0.f;
    int cnt = 0;
    for (int t = b; t < e2; t++) {
        int s = es[t];
        if ((unsigned)s < (unsigned)NN) { acc += x[(size_t)s * CC + c]; cnt++; }
    }
    meanb[(size_t)n * CC + c] = acc / fmaxf((float)cnt, 1.0f);
}

// ---------------------------------------------------------------------------
// SAGE layer: out = relu(a@Ws + mean@Wn + b), 8 nodes/block
// ---------------------------------------------------------------------------
__global__ __launch_bounds__(128)
void k_layer(const float* __restrict__ a, const float* __restrict__ mb,
             const float* __restrict__ Ws, const float* __restrict__ Wn,
             const float* __restrict__ bias, float* __restrict__ out)
{
    __shared__ float as[8][CC], ms[8][CC];
    const int tid = threadIdx.x;
    const int n0 = blockIdx.x * 8;
    #pragma unroll
    for (int m = 0; m < 8; m++) {
        as[m][tid] = a[(size_t)(n0 + m) * CC + tid];
        ms[m][tid] = mb[(size_t)(n0 + m) * CC + tid];
    }
    __syncthreads();
    float acc[8];
    #pragma unroll
    for (int m = 0; m < 8; m++) acc[m] = bias[tid];
    for (int j = 0; j < CC; j++) {
        float ws = Ws[j * CC + tid], wn = Wn[j * CC + tid];
        #pragma unroll
        for (int m = 0; m < 8; m++) acc[m] += as[m][j] * ws + ms[m][j] * wn;
    }
    #pragma unroll
    for (int m = 0; m < 8; m++)
        out[(size_t)(n0 + m) * CC + tid] = fmaxf(acc[m], 0.f);
}

// ---------------------------------------------------------------------------
// Head: out = h2 @ W_head + b_head, fp32 output
// ---------------------------------------------------------------------------
__global__ __launch_bounds__(128)
void k_head(const float* __restrict__ h2, const float* __restrict__ W,
            const float* __restrict__ bias, float* __restrict__ out)
{
    __shared__ float hsh[8][CC];
    const int tid = threadIdx.x;
    const int n0 = blockIdx.x * 8;
    #pragma unroll
    for (int m = 0; m < 8; m++) hsh[m][tid] = h2[(size_t)(n0 + m) * CC + tid];
    __syncthreads();
    float acc[8];
    #pragma unroll
    for (int m = 0; m < 8; m++) acc[m] = bias[tid];
    for (int j = 0; j < CC; j++) {
        float w = W[j * OO + tid];
        #pragma unroll
        for (int m = 0; m < 8; m++) acc[m] += hsh[m][j] * w;
    }
    #pragma unroll
    for (int m = 0; m < 8; m++)
        out[(size_t)(n0 + m) * OO + tid] = acc[m];
}

// ---------------------------------------------------------------------------
extern "C" void kernel_launch(void* const* d_in, const int* in_sizes, int n_in,
                              void* d_out, int out_size, void* d_ws, size_t ws_size,
                              hipStream_t stream)
{
    const float* x_raw      = (const float*)d_in[0];
    const float* eps        = (const float*)d_in[1];
    const float* col_logit  = (const float*)d_in[2];
    const float* type_logit = (const float*)d_in[3];
    const float* W_enc      = (const float*)d_in[4];
    const float* b_enc      = (const float*)d_in[5];
    const float* W_mu       = (const float*)d_in[6];
    const float* b_mu       = (const float*)d_in[7];
    const float* W_lv       = (const float*)d_in[8];
    const float* b_lv       = (const float*)d_in[9];
    const float* W_self1    = (const float*)d_in[10];
    const float* W_nbr1     = (const float*)d_in[11];
    const float* b1         = (const float*)d_in[12];
    const float* W_self2    = (const float*)d_in[13];
    const float* W_nbr2     = (const float*)d_in[14];
    const float* b2         = (const float*)d_in[15];
    const float* W_head     = (const float*)d_in[16];
    const float* b_head     = (const float*)d_in[17];
    float* out              = (float*)d_out;   // fp32 output, per reference dtype

    char* base = (char*)d_ws;
    size_t off = 0;
    auto alloc = [&](size_t bytes) { size_t o = off; off = (off + bytes + 255) & ~(size_t)255; return o; };

    const size_t MAT  = (size_t)NN * CC * 4;   // 8.39 MB

    float* z32    = (float*)(base + alloc(MAT));
    float* zn32   = (float*)(base + alloc(MAT));
    float* slotD  = (float*)(base + alloc(MAT));   // sim overlay (S=128) then h1
    float* meanb  = (float*)(base + alloc(MAT));
    unsigned short* znb = (unsigned short*)(base + alloc((size_t)NN * CC * 2));  // 4 MB
    float* simmax = (float*)(base + alloc((size_t)2048 * NT * 4));  // 2 MB (max stripe)
    int*   nbr    = (int*)(base + alloc((size_t)NN * KP1 * 4));
    int*   deg    = (int*)(base + alloc((size_t)NN * 4));
    int*   rp     = (int*)(base + alloc((size_t)(NN + 1) * 4));
    int*   wp     = (int*)(base + alloc((size_t)NN * 4));
    int*   es     = (int*)(base + alloc((size_t)NN * KP1 * 4));
    size_t fixed_small = off;

    // optional fp64 zn (16.78 MB)
    int use64 = (ws_size >= fixed_small + (size_t)NN * CC * 8 + 4096) ? 1 : 0;
    double* zn64 = nullptr;
    if (use64) zn64 = (double*)(base + alloc((size_t)NN * CC * 8));

    // sim stripe (bf16): dedicated if it fits, else S=128 overlay in slotD
    size_t avail = (ws_size > off) ? (ws_size - off - 4096) : 0;
    int S = 2048;
    while (S > 128 && (size_t)S * SIMN * 2 > avail) S >>= 1;
    unsigned short* sim;
    if ((size_t)S * SIMN * 2 <= avail && S > 128) {
        sim = (unsigned short*)(base + alloc((size_t)S * SIMN * 2));
    } else {
        S = 128;                                  // 4 MB, fits in slotD (8.39 MB)
        sim = (unsigned short*)slotD;
    }

    float* h1 = slotD;                            // after stripes, slotD becomes h1
    float* h2 = zn32;                             // zn32 dead after topk

    k_init<<<(NN * KP1 + 255) / 256, 256, 0, stream>>>(deg, nbr);

    k_pre<<<NN / 8, 128, 0, stream>>>(x_raw, eps, col_logit, type_logit,
                                      W_enc, b_enc, W_mu, b_mu, W_lv, b_lv,
                                      zn64, z32, zn32, znb, use64);

    for (int row0 = 0; row0 < NN; row0 += S) {
        dim3 g(S / 128, SIMN / 128);
        k_sim<<<g, 256, 0, stream>>>(znb, row0, sim, simmax);
        k_topk<<<S, 256, 0, stream>>>(sim, simmax, row0, zn64, zn32, nbr, deg, use64);
    }

    k_scan<<<1, 256, 0, stream>>>(deg, rp, wp);
    int eb = (NN * KP1 + 255) / 256;
    k_fill<<<eb, 256, 0, stream>>>(nbr, wp, es);

    k_gather<<<NN, 128, 0, stream>>>(z32, rp, es, meanb);
    k_layer<<<NN / 8, 128, 0, stream>>>(z32, meanb, W_self1, W_nbr1, b1, h1);
    k_gather<<<NN, 128, 0, stream>>>(h1, rp, es, meanb);
    k_layer<<<NN / 8, 128, 0, stream>>>(h1, meanb, W_self2, W_nbr2, b2, h2);
    k_head<<<NN / 8, 128, 0, stream>>>(h2, W_head, b_head, out);

    (void)in_sizes; (void)n_in; (void)out_size;
}